// Round 13
// baseline (391.897 us; speedup 1.0000x reference)
//
#include <hip/hip_runtime.h>

#define NE 524288
#define NN 32768
#define NB 1024

#define F4(p) (*(const float4*)(p))

typedef __bf16 bf16x8 __attribute__((ext_vector_type(8)));
typedef float  f32x4  __attribute__((ext_vector_type(4)));

__device__ __forceinline__ float sigmoidf_(float v) { return 1.f / (1.f + expf(-v)); }

__device__ __forceinline__ void bf16split(float f, short &hi, short &lo) {
  unsigned u = __float_as_uint(f);
  unsigned rh = (u + 0x7FFFu + ((u >> 16) & 1u)) >> 16;
  float fh = __uint_as_float(rh << 16);
  float fl = f - fh;
  unsigned u2 = __float_as_uint(fl);
  unsigned rl = (u2 + 0x7FFFu + ((u2 >> 16) & 1u)) >> 16;
  hi = (short)rh; lo = (short)rl;
}

__device__ __forceinline__ unsigned short f2bf(float f) {
  unsigned u = __float_as_uint(f);
  return (unsigned short)((u + 0x7FFFu + ((u >> 16) & 1u)) >> 16);
}
__device__ __forceinline__ float bf2f(unsigned short h) {
  return __uint_as_float(((unsigned)h) << 16);
}

__device__ __forceinline__ void ld32(float* xr, const float* p) {
#pragma unroll
  for (int i = 0; i < 32; i += 4) {
    float4 v = F4(&p[i]);
    xr[i] = v.x; xr[i+1] = v.y; xr[i+2] = v.z; xr[i+3] = v.w;
  }
}

__device__ __forceinline__ float dot32r(const float* __restrict__ w, const float* xr) {
  float s = 0.f;
#pragma unroll
  for (int i = 0; i < 32; i += 4) {
    float4 ww = F4(&w[i]);
    s = fmaf(xr[i],   ww.x, s);
    s = fmaf(xr[i+1], ww.y, s);
    s = fmaf(xr[i+2], ww.z, s);
    s = fmaf(xr[i+3], ww.w, s);
  }
  return s;
}

// ---------------- CSR build ----------------
__global__ __launch_bounds__(256) void hist_kernel(const int* __restrict__ ei, int* __restrict__ cnt) {
  const int e = blockIdx.x*256 + threadIdx.x;
  atomicAdd(&cnt[ei[NE + e]], 1);
}

__global__ __launch_bounds__(1024) void scan_kernel(
    const int* __restrict__ cnt, int* __restrict__ off, int* __restrict__ cur)
{
  __shared__ int wsum[16];
  const int t = threadIdx.x;
  int local[32];
  const int base = t*32;
  int s = 0;
#pragma unroll
  for (int i = 0; i < 32; ++i) { local[i] = cnt[base+i]; s += local[i]; }
  int pre = s;
  const int lane = t & 63;
#pragma unroll
  for (int o = 1; o < 64; o <<= 1) { int v = __shfl_up(pre, o); if (lane >= o) pre += v; }
  if (lane == 63) wsum[t >> 6] = pre;
  __syncthreads();
  if (t == 0) { int a = 0; for (int w = 0; w < 16; ++w) { int v = wsum[w]; wsum[w] = a; a += v; } }
  __syncthreads();
  int excl = wsum[t >> 6] + pre - s;
#pragma unroll
  for (int i = 0; i < 32; ++i) { off[base+i] = excl; cur[base+i] = excl; excl += local[i]; }
  if (t == 1023) off[NN] = excl;
}

// edge record: {src_as_float, d, 1/(1+d), exp(-d)}
__global__ __launch_bounds__(256) void scatter_kernel(
    const float* __restrict__ pos, const int* __restrict__ ei,
    int* __restrict__ cur, float4* __restrict__ csr_rec)
{
  const int e = blockIdx.x*256 + threadIdx.x;
  const int s = ei[e];
  const int d = ei[NE + e];
  float dx = pos[d*3+0] - pos[s*3+0];
  float dy = pos[d*3+1] - pos[s*3+1];
  float dz = pos[d*3+2] - pos[s*3+2];
  float dist = sqrtf(dx*dx + dy*dy + dz*dz + 1e-12f);
  const int slot = atomicAdd(&cur[d], 1);
  csr_rec[slot] = make_float4(__int_as_float(s), dist, 1.f/(1.f + dist), expf(-dist));
}

// ---------------- weight prep: split-bf16, MFMA-frag-major ----------------
__device__ __forceinline__ void pack_decode(int r, int N, int &k, int &n) {
  const int j = r & 7, lane = (r >> 3) & 63, rest = r >> 9;
  const int NT = N >> 4;
  const int t = rest % NT, kc = rest / NT;
  k = kc*32 + (lane >> 4)*8 + j;
  n = t*16 + (lane & 15);
}

// segment offsets (elements)
#define W1AB_OFF 0        // l*32768, K=128 N=256
#define W2_OFF   98304    // l*16384, K=128 N=128
#define WIN_OFF  147456   // K=128 N=384
#define WOUT_OFF 196608   // K=128 N=128
#define EMB_OFF  212992   // K=64  N=128
#define PK_TOTAL 221184

__global__ __launch_bounds__(256) void prep_kernel(
    const float* __restrict__ mp_W1, const float* __restrict__ mp_W2,
    const float* __restrict__ win, const float* __restrict__ wout,
    const float* __restrict__ emb_W, const float* __restrict__ mp_b1,
    short* __restrict__ bh, short* __restrict__ bl, float* __restrict__ pqbias)
{
  const int i = blockIdx.x*256 + threadIdx.x;
  if (i < 768) { const int l = i >> 8, t = i & 255; pqbias[i] = t < 128 ? mp_b1[l*128 + t] : 0.f; }
  if (i >= PK_TOTAL) return;
  int k, n; float v;
  if (i < W2_OFF) {
    const int l = i / 32768, r = i % 32768;
    pack_decode(r, 256, k, n);
    const float* W = mp_W1 + (size_t)l*259*128;
    v = (n < 128) ? W[k*128 + n] : W[(128+k)*128 + (n-128)];
  } else if (i < WIN_OFF) {
    const int q = i - W2_OFF, l = q / 16384, r = q % 16384;
    pack_decode(r, 128, k, n);
    v = mp_W2[(size_t)l*16384 + k*128 + n];
  } else if (i < WOUT_OFF) {
    pack_decode(i - WIN_OFF, 384, k, n);
    v = win[n*128 + k];
  } else if (i < EMB_OFF) {
    pack_decode(i - WOUT_OFF, 128, k, n);
    v = wout[n*128 + k];
  } else {
    pack_decode(i - EMB_OFF, 128, k, n);   // K=64 segment: k < 64 by construction
    v = emb_W[k*128 + n];
  }
  short h_, lo; bf16split(v, h_, lo);
  bh[i] = h_; bl[i] = lo;
}

// ---------------- gate prep: fold input gates into head first-layer weights ----------------
// meW1g[p][k][h] = meW1[p][k][h]*sigmoid(mol_gate[p][k]); leW1g likewise.
__global__ __launch_bounds__(256) void gate_prep_kernel(
    const float* __restrict__ meW1, const float* __restrict__ mol_gate,
    const float* __restrict__ leW1, const float* __restrict__ lrn_gate,
    float* __restrict__ meW1g, float* __restrict__ leW1g)
{
  const int i = blockIdx.x*256 + threadIdx.x;
  if (i < 51200) {
    const int p = i / 12800, r = i % 12800, k = r >> 6;
    meW1g[i] = meW1[i] * sigmoidf_(mol_gate[p*200 + k]);
  } else if (i < 67584) {
    const int q = i - 51200;
    const int p = q / 4096, r = q % 4096, k = r >> 6;
    leW1g[q] = leW1[q] * sigmoidf_(lrn_gate[p*64 + k]);
  }
}

// ---------------- generic MFMA GEMM: C[M][·] = op(A[M][K] @ B + bias) ----------------
__global__ __launch_bounds__(256, 2) void mfma_gemm_kernel(
    const float* __restrict__ A, int lda, int K,
    const short* __restrict__ Bh, const short* __restrict__ Bl,
    const float* __restrict__ bias, float* __restrict__ C, int ncols, int ldc,
    int relu, unsigned short* __restrict__ qbf)
{
  const int lane = threadIdx.x & 63, wid = threadIdx.x >> 6;
  const int m0 = blockIdx.x * 128 + wid * 32;
  const int n0 = blockIdx.y * 64;
  const int NT = ncols >> 4;
  const int cl = lane & 15, kg = lane >> 4;
  const int KC = K >> 5;

  f32x4 acc[2][4];
#pragma unroll
  for (int s = 0; s < 2; ++s)
#pragma unroll
    for (int t = 0; t < 4; ++t) acc[s][t] = (f32x4){0.f,0.f,0.f,0.f};

  for (int kc = 0; kc < KC; ++kc) {
    bf16x8 Ah[2], Al[2];
#pragma unroll
    for (int s = 0; s < 2; ++s) {
      const float* ap = &A[(size_t)(m0 + s*16 + cl)*lda + kc*32 + kg*8];
      const float4 f0 = F4(ap), f1 = F4(ap + 4);
      const float fv[8] = {f0.x,f0.y,f0.z,f0.w,f1.x,f1.y,f1.z,f1.w};
      union { short s[8]; bf16x8 b; } uh, ul;
#pragma unroll
      for (int j = 0; j < 8; ++j) bf16split(fv[j], uh.s[j], ul.s[j]);
      Ah[s] = uh.b; Al[s] = ul.b;
    }
    bf16x8 Bfh[4], Bfl[4];
#pragma unroll
    for (int t = 0; t < 4; ++t) {
      const size_t off = (((size_t)(kc*NT + (n0 >> 4) + t))*64 + lane)*8;
      Bfh[t] = *(const bf16x8*)&Bh[off];
      Bfl[t] = *(const bf16x8*)&Bl[off];
    }
#pragma unroll
    for (int s = 0; s < 2; ++s)
#pragma unroll
      for (int t = 0; t < 4; ++t)
        acc[s][t] = __builtin_amdgcn_mfma_f32_16x16x32_bf16(Ah[s], Bfh[t], acc[s][t], 0, 0, 0);
#pragma unroll
    for (int s = 0; s < 2; ++s)
#pragma unroll
      for (int t = 0; t < 4; ++t)
        acc[s][t] = __builtin_amdgcn_mfma_f32_16x16x32_bf16(Ah[s], Bfl[t], acc[s][t], 0, 0, 0);
#pragma unroll
    for (int s = 0; s < 2; ++s)
#pragma unroll
      for (int t = 0; t < 4; ++t)
        acc[s][t] = __builtin_amdgcn_mfma_f32_16x16x32_bf16(Al[s], Bfh[t], acc[s][t], 0, 0, 0);
  }

#pragma unroll
  for (int t = 0; t < 4; ++t) {
    const int col = n0 + t*16 + cl;
    const float bv = bias[col];
#pragma unroll
    for (int s = 0; s < 2; ++s) {
      const int rbase = m0 + s*16 + kg*4;
#pragma unroll
      for (int r = 0; r < 4; ++r) {
        float v = acc[s][t][r] + bv;
        if (relu) v = fmaxf(v, 0.f);
        if (qbf && col >= 128)
          qbf[(size_t)(rbase + r)*128 + (col - 128)] = f2bf(v);
        else
          C[(size_t)(rbase + r)*ldc + col] = v;
      }
    }
  }
}

// ---------------- MFMA GEMM + residual + LN ----------------
__global__ __launch_bounds__(256, 2) void mfma_gemm_ln_kernel(
    const float* __restrict__ A, int lda,
    const short* __restrict__ Bh, const short* __restrict__ Bl,
    const float* __restrict__ b2, const int* __restrict__ csr_off,
    const float* __restrict__ g, const float* __restrict__ bb,
    float* __restrict__ x)
{
  const int lane = threadIdx.x & 63, wid = threadIdx.x >> 6;
  const int m0 = blockIdx.x * 64 + wid * 16;
  const int cl = lane & 15, kg = lane >> 4;

  bf16x8 Ah[4], Al[4];
#pragma unroll
  for (int kc = 0; kc < 4; ++kc) {
    const float* ap = &A[(size_t)(m0 + cl)*lda + kc*32 + kg*8];
    const float4 f0 = F4(ap), f1 = F4(ap + 4);
    const float fv[8] = {f0.x,f0.y,f0.z,f0.w,f1.x,f1.y,f1.z,f1.w};
    union { short s[8]; bf16x8 b; } uh, ul;
#pragma unroll
    for (int j = 0; j < 8; ++j) bf16split(fv[j], uh.s[j], ul.s[j]);
    Ah[kc] = uh.b; Al[kc] = ul.b;
  }

  f32x4 acc[8];
#pragma unroll
  for (int t = 0; t < 8; ++t) acc[t] = (f32x4){0.f,0.f,0.f,0.f};

#pragma unroll
  for (int kc = 0; kc < 4; ++kc) {
    bf16x8 Bfh[8], Bfl[8];
#pragma unroll
    for (int t = 0; t < 8; ++t) {
      const size_t off = (((size_t)(kc*8 + t))*64 + lane)*8;
      Bfh[t] = *(const bf16x8*)&Bh[off];
      Bfl[t] = *(const bf16x8*)&Bl[off];
    }
#pragma unroll
    for (int t = 0; t < 8; ++t)
      acc[t] = __builtin_amdgcn_mfma_f32_16x16x32_bf16(Ah[kc], Bfh[t], acc[t], 0, 0, 0);
#pragma unroll
    for (int t = 0; t < 8; ++t)
      acc[t] = __builtin_amdgcn_mfma_f32_16x16x32_bf16(Ah[kc], Bfl[t], acc[t], 0, 0, 0);
#pragma unroll
    for (int t = 0; t < 8; ++t)
      acc[t] = __builtin_amdgcn_mfma_f32_16x16x32_bf16(Al[kc], Bfh[t], acc[t], 0, 0, 0);
  }

  const int r0 = m0 + kg*4;
  float sflag[4];
#pragma unroll
  for (int r = 0; r < 4; ++r)
    sflag[r] = (csr_off[r0 + r + 1] > csr_off[r0 + r]) ? 1.f : 0.f;

  float ps[4] = {0.f,0.f,0.f,0.f}, pq[4] = {0.f,0.f,0.f,0.f};
  float yv[8][4];
#pragma unroll
  for (int t = 0; t < 8; ++t) {
    const int col = t*16 + cl;
    const float b2v = b2[col];
#pragma unroll
    for (int r = 0; r < 4; ++r) {
      const float y = acc[t][r] + sflag[r]*b2v + x[(size_t)(r0 + r)*128 + col];
      yv[t][r] = y;
      ps[r] += y;
      pq[r] = fmaf(y, y, pq[r]);
    }
  }
#pragma unroll
  for (int o = 1; o < 16; o <<= 1) {
#pragma unroll
    for (int r = 0; r < 4; ++r) { ps[r] += __shfl_xor(ps[r], o); pq[r] += __shfl_xor(pq[r], o); }
  }
#pragma unroll
  for (int r = 0; r < 4; ++r) {
    const float mu = ps[r] * (1.f/128.f);
    const float var = pq[r]*(1.f/128.f) - mu*mu;
    const float rstd = rsqrtf(var + 1e-5f);
#pragma unroll
    for (int t = 0; t < 8; ++t) {
      const int col = t*16 + cl;
      x[(size_t)(r0 + r)*128 + col] = (yv[t][r] - mu)*rstd*g[col] + bb[col];
    }
  }
}

// ---------------- aggregation: P[n] <- mean_e relu(P[n]+Qbf[src]+df@W1c) ----------------
__global__ __launch_bounds__(256, 6) void agg_kernel(
    float* __restrict__ P, const unsigned short* __restrict__ Qbf,
    const int* __restrict__ csr_off, const float4* __restrict__ csr_rec,
    const float* __restrict__ W1)
{
  const int tid = threadIdx.x;
  const int node = blockIdx.x*4 + (tid >> 6);
  const int lane = tid & 63;
  const int c0 = lane*2;
  const int off0 = csr_off[node], off1 = csr_off[node+1];

  const float* __restrict__ w1c = W1 + 256*128;
  const float w00 = w1c[c0],       w01 = w1c[c0+1];
  const float w10 = w1c[128+c0],   w11 = w1c[128+c0+1];
  const float w20 = w1c[256+c0],   w21 = w1c[256+c0+1];
  const float2 p = *(const float2*)&P[(size_t)node*128 + c0];

  float a0 = 0.f, a1 = 0.f;
  int e = off0;
  for (; e + 8 <= off1; e += 8) {
    float4 rc[8];
#pragma unroll
    for (int j = 0; j < 8; ++j) rc[j] = csr_rec[e+j];
    ushort2 qv[8];
#pragma unroll
    for (int j = 0; j < 8; ++j)
      qv[j] = *(const ushort2*)&Qbf[(size_t)__float_as_int(rc[j].x)*128 + c0];
#pragma unroll
    for (int j = 0; j < 8; ++j) {
      float h0 = p.x + bf2f(qv[j].x);
      h0 = fmaf(rc[j].y, w00, h0); h0 = fmaf(rc[j].z, w10, h0); h0 = fmaf(rc[j].w, w20, h0);
      float h1 = p.y + bf2f(qv[j].y);
      h1 = fmaf(rc[j].y, w01, h1); h1 = fmaf(rc[j].z, w11, h1); h1 = fmaf(rc[j].w, w21, h1);
      a0 += fmaxf(h0, 0.f);
      a1 += fmaxf(h1, 0.f);
    }
  }
  for (; e < off1; ++e) {
    const float4 rc = csr_rec[e];
    const ushort2 qv = *(const ushort2*)&Qbf[(size_t)__float_as_int(rc.x)*128 + c0];
    float h0 = p.x + bf2f(qv.x);
    h0 = fmaf(rc.y, w00, h0); h0 = fmaf(rc.z, w10, h0); h0 = fmaf(rc.w, w20, h0);
    float h1 = p.y + bf2f(qv.y);
    h1 = fmaf(rc.y, w01, h1); h1 = fmaf(rc.z, w11, h1); h1 = fmaf(rc.w, w21, h1);
    a0 += fmaxf(h0, 0.f);
    a1 += fmaxf(h1, 0.f);
  }
  const int deg = off1 - off0;
  const float rc_ = deg > 0 ? 1.f/(float)deg : 1.f;
  *(float2*)&P[(size_t)node*128 + c0] = make_float2(a0*rc_, a1*rc_);
}

// ---------------- per-molecule attention on dqkv[n][384]; O -> dv slot ----------------
__global__ __launch_bounds__(128) void attn_kernel(float* __restrict__ dqkv)
{
  __shared__ float sk[32*132];
  __shared__ float sv[32*132];
  const int tid = threadIdx.x;
  const int b = blockIdx.x;

  for (int idx = tid; idx < 1024; idx += 128) {
    const int a = idx >> 5, c4 = idx & 31;
    *(float4*)&sk[a*132 + c4*4] = F4(&dqkv[(size_t)(b*32+a)*384 + 128 + c4*4]);
    *(float4*)&sv[a*132 + c4*4] = F4(&dqkv[(size_t)(b*32+a)*384 + 256 + c4*4]);
  }
  __syncthreads();

  const int h = tid >> 5, qr = tid & 31;
  float qreg[32];
  ld32(qreg, &dqkv[(size_t)(b*32+qr)*384 + h*32]);

  float sc[32];
#pragma unroll
  for (int k = 0; k < 32; ++k)
    sc[k] = dot32r(&sk[k*132 + h*32], qreg) * 0.17677669529663687f;
  float mx = sc[0];
#pragma unroll
  for (int k = 1; k < 32; ++k) mx = fmaxf(mx, sc[k]);
  float se = 0.f;
#pragma unroll
  for (int k = 0; k < 32; ++k) { sc[k] = expf(sc[k] - mx); se += sc[k]; }
  const float inv = 1.f / se;

  __syncthreads();

  float od[32];
#pragma unroll
  for (int i = 0; i < 32; ++i) od[i] = 0.f;
#pragma unroll 4
  for (int k = 0; k < 32; ++k) {
    const float w = sc[k] * inv;
    const float* vr = &sv[k*132 + h*32];
#pragma unroll
    for (int i = 0; i < 32; i += 4) {
      float4 v = F4(&vr[i]);
      od[i]   = fmaf(w, v.x, od[i]);
      od[i+1] = fmaf(w, v.y, od[i+1]);
      od[i+2] = fmaf(w, v.z, od[i+2]);
      od[i+3] = fmaf(w, v.w, od[i+3]);
    }
  }
#pragma unroll
  for (int i = 0; i < 32; i += 4)
    *(float4*)&sk[qr*132 + h*32 + i] = make_float4(od[i], od[i+1], od[i+2], od[i+3]);
  __syncthreads();

  for (int idx = tid; idx < 1024; idx += 128) {
    const int a = idx >> 5, c4 = idx & 31;
    *(float4*)&dqkv[(size_t)(b*32+a)*384 + 256 + c4*4] = F4(&sk[a*132 + c4*4]);
  }
}

// ---------------- fused pooling + proj + wave-autonomous per-property head ----------------
// block = 256 threads (4 waves) = 1 molecule. After one barrier (slrn/sexpl/smolf
// published), each wave = one property runs the 6-stage MLP chain with activations in
// registers (cross-lane __shfl broadcast) and ZERO further barriers.
__global__ __launch_bounds__(256) void pool_head_kernel(
    const float* __restrict__ att, const float* __restrict__ x,
    const float* __restrict__ pW, const float* __restrict__ pb,
    const float* __restrict__ molf,
    const float* __restrict__ meW1g, const float* __restrict__ meb1,
    const float* __restrict__ meW2, const float* __restrict__ meb2,
    const float* __restrict__ leW1g, const float* __restrict__ leb1,
    const float* __restrict__ leW2, const float* __restrict__ leb2,
    const float* __restrict__ fW1, const float* __restrict__ fb1,
    const float* __restrict__ fW2, const float* __restrict__ fb2,
    const float* __restrict__ hW1, const float* __restrict__ hb1,
    const float* __restrict__ hW2, const float* __restrict__ hb2,
    float* __restrict__ out)
{
  const int b = blockIdx.x, tid = threadIdx.x;
  __shared__ float satt[4224];
  __shared__ float sx[4224];
  __shared__ float aw_l[32];
  __shared__ float spool[512];
  __shared__ float slrn[64];
  __shared__ float sexpl[128];
  __shared__ float smolf[200];

  for (int idx = tid; idx < 1024; idx += 256) {
    const int a = idx >> 5, c4 = idx & 31;
    *(float4*)&satt[a*132 + c4*4] = F4(&att[(size_t)(b*32+a)*128 + c4*4]);
    *(float4*)&sx[a*132 + c4*4]   = F4(&x[(size_t)(b*32+a)*128 + c4*4]);
  }
  if (tid < 200) smolf[tid] = molf[(size_t)b*200 + tid];
  __syncthreads();

  { // aw logits: 8 threads/row
    const int a = tid >> 3, q8 = tid & 7;
    float sp = 0.f;
#pragma unroll
    for (int i = 0; i < 16; ++i)
      sp = fmaf(satt[a*132 + q8*16 + i], sx[a*132 + q8*16 + i], sp);
    sp += __shfl_xor(sp, 1);
    sp += __shfl_xor(sp, 2);
    sp += __shfl_xor(sp, 4);
    if (q8 == 0) aw_l[a] = sp;
  }
  __syncthreads();

  if (tid < 128) { // pooling per column
    float awr[32];
    float mxl = aw_l[0];
#pragma unroll
    for (int a = 1; a < 32; ++a) mxl = fmaxf(mxl, aw_l[a]);
    float se = 0.f;
#pragma unroll
    for (int a = 0; a < 32; ++a) { awr[a] = expf(aw_l[a] - mxl); se += awr[a]; }
    const float inv = 1.f / se;
    const int c = tid;
    float mx = -3.4e38f, sm = 0.f, wm = 0.f, ex = 0.f;
#pragma unroll
    for (int a = 0; a < 32; ++a) {
      const float v = satt[a*132 + c];
      mx = fmaxf(mx, v);
      sm += v;
      wm = fmaf(v, awr[a], wm);
      ex += sx[a*132 + c];
    }
    wm *= inv;
    const float mean = sm * 0.03125f;
    float s2 = 0.f;
#pragma unroll
    for (int a = 0; a < 32; ++a) {
      const float d = satt[a*132 + c] - mean;
      s2 = fmaf(d, d, s2);
    }
    const float stdp = sqrtf(s2 * (1.f/31.f));  // ddof=1
    sexpl[c]       = ex * 0.03125f;
    spool[c]       = wm;
    spool[128 + c] = mx;
    spool[256 + c] = mean;
    spool[384 + c] = stdp;
  }
  __syncthreads();

  if (tid < 64) { // proj -> slrn
    const int k = tid >> 4, qq = tid & 15;
    const float* pk = pW + k*2048;
    float s0 = 0.f, s1 = 0.f, s2 = 0.f, s3 = 0.f;
    for (int h2 = 0; h2 < 128; h2 += 4) {
      s0 = fmaf(spool[k*128 + h2],   pk[h2*16 + qq],     s0);
      s1 = fmaf(spool[k*128 + h2+1], pk[(h2+1)*16 + qq], s1);
      s2 = fmaf(spool[k*128 + h2+2], pk[(h2+2)*16 + qq], s2);
      s3 = fmaf(spool[k*128 + h2+3], pk[(h2+3)*16 + qq], s3);
    }
    slrn[tid] = pb[k*16 + qq] + (s0+s1) + (s2+s3);
  }
  __syncthreads();  // slrn/sexpl/smolf published -> head phase, NO barriers below

  const int p = tid >> 6, l = tid & 63;

  // --- me1: relu(smolf @ meW1g_p + meb1), K=200, output m1 (1/lane) ---
  float m1;
  {
    const float* w = meW1g + p*12800 + l;
    float a[8] = {0.f,0.f,0.f,0.f,0.f,0.f,0.f,0.f};
    for (int k = 0; k < 200; k += 8) {
      float wv[8], av[8];
#pragma unroll
      for (int j = 0; j < 8; ++j) wv[j] = w[(k+j)*64];
#pragma unroll
      for (int j = 0; j < 8; ++j) av[j] = smolf[k+j];
#pragma unroll
      for (int j = 0; j < 8; ++j) a[j] = fmaf(av[j], wv[j], a[j]);
    }
    m1 = fmaxf(((a[0]+a[1])+(a[2]+a[3])) + ((a[4]+a[5])+(a[6]+a[7])) + meb1[p*64 + l], 0.f);
  }
  // --- le1: relu(slrn @ leW1g_p + leb1), K=64 ---
  float l1;
  {
    const float* w = leW1g + p*4096 + l;
    float a[8] = {0.f,0.f,0.f,0.f,0.f,0.f,0.f,0.f};
    for (int k = 0; k < 64; k += 8) {
      float wv[8], av[8];
#pragma unroll
      for (int j = 0; j < 8; ++j) wv[j] = w[(k+j)*64];
#pragma unroll
      for (int j = 0; j < 8; ++j) av[j] = slrn[k+j];
#pragma unroll
      for (int j = 0; j < 8; ++j) a[j] = fmaf(av[j], wv[j], a[j]);
    }
    l1 = fmaxf(((a[0]+a[1])+(a[2]+a[3])) + ((a[4]+a[5])+(a[6]+a[7])) + leb1[p*64 + l], 0.f);
  }
  // --- me2 / le2: K=64 each, inputs m1/l1 via shuffle ---
  float m2, l2;
  {
    const float* w  = meW2 + p*4096 + l;
    const float* w2 = leW2 + p*4096 + l;
    float a[8] = {0.f,0.f,0.f,0.f,0.f,0.f,0.f,0.f};
    float c[8] = {0.f,0.f,0.f,0.f,0.f,0.f,0.f,0.f};
    for (int k = 0; k < 64; k += 8) {
      float wv[8], vv[8], av[8], bv[8];
#pragma unroll
      for (int j = 0; j < 8; ++j) wv[j] = w[(k+j)*64];
#pragma unroll
      for (int j = 0; j < 8; ++j) vv[j] = w2[(k+j)*64];
#pragma unroll
      for (int j = 0; j < 8; ++j) { av[j] = __shfl(m1, k+j); bv[j] = __shfl(l1, k+j); }
#pragma unroll
      for (int j = 0; j < 8; ++j) {
        a[j] = fmaf(av[j], wv[j], a[j]);
        c[j] = fmaf(bv[j], vv[j], c[j]);
      }
    }
    m2 = ((a[0]+a[1])+(a[2]+a[3])) + ((a[4]+a[5])+(a[6]+a[7])) + meb2[p*64 + l];
    l2 = ((c[0]+c[1])+(c[2]+c[3])) + ((c[4]+c[5])+(c[6]+c[7])) + leb2[p*64 + l];
  }
  // --- fus1: K=256 (expl 0..127 LDS, m2 128..191 shfl, l2 192..255 shfl); cols l, l+64 ---
  float f1a, f1b;
  {
    const float* w = fW1 + p*32768;
    float a[8] = {0.f,0.f,0.f,0.f,0.f,0.f,0.f,0.f};
    float c[8] = {0.f,0.f,0.f,0.f,0.f,0.f,0.f,0.f};
    for (int k = 0; k < 128; k += 8) {
      float w0[8], w1[8], av[8];
#pragma unroll
      for (int j = 0; j < 8; ++j) w0[j] = w[(k+j)*128 + l];
#pragma unroll
      for (int j = 0; j < 8; ++j) w1[j] = w[(k+j)*128 + 64 + l];
#pragma unroll
      for (int j = 0; j < 8; ++j) av[j] = sexpl[k+j];
#pragma unroll
      for (int j = 0; j < 8; ++j) {
        a[j] = fmaf(av[j], w0[j], a[j]);
        c[j] = fmaf(av[j], w1[j], c[j]);
      }
    }
    for (int k = 0; k < 64; k += 8) {
      float w0[8], w1[8], av[8];
#pragma unroll
      for (int j = 0; j < 8; ++j) w0[j] = w[(128+k+j)*128 + l];
#pragma unroll
      for (int j = 0; j < 8; ++j) w1[j] = w[(128+k+j)*128 + 64 + l];
#pragma unroll
      for (int j = 0; j < 8; ++j) av[j] = __shfl(m2, k+j);
#pragma unroll
      for (int j = 0; j < 8; ++j) {
        a[j] = fmaf(av[j], w0[j], a[j]);
        c[j] = fmaf(av[j], w1[j], c[j]);
      }
    }
    for (int k = 0; k < 64; k += 8) {
      float w0[8], w1[8], av[8];
#pragma unroll
      for (int j = 0; j < 8; ++j) w0[j] = w[(192+k+j)*128 + l];
#pragma unroll
      for (int j = 0; j < 8; ++j) w1[j] = w[(192+k+j)*128 + 64 + l];
#pragma unroll
      for (int j = 0; j < 8; ++j) av[j] = __shfl(l2, k+j);
#pragma unroll
      for (int j = 0; j < 8; ++j) {
        a[j] = fmaf(av[j], w0[j], a[j]);
        c[j] = fmaf(av[j], w1[j], c[j]);
      }
    }
    f1a = fmaxf(((a[0]+a[1])+(a[2]+a[3])) + ((a[4]+a[5])+(a[6]+a[7])) + fb1[p*128 + l], 0.f);
    f1b = fmaxf(((c[0]+c[1])+(c[2]+c[3])) + ((c[4]+c[5])+(c[6]+c[7])) + fb1[p*128 + 64 + l], 0.f);
  }
  // --- fus2: K=128 (f1a rows 0..63, f1b rows 64..127, shfl) ---
  float f2;
  {
    const float* w = fW2 + p*8192 + l;
    float a[8] = {0.f,0.f,0.f,0.f,0.f,0.f,0.f,0.f};
    for (int k = 0; k < 64; k += 8) {
      float wv[8], av[8];
#pragma unroll
      for (int j = 0; j < 8; ++j) wv[j] = w[(k+j)*64];
#pragma unroll
      for (int j = 0; j < 8; ++j) av[j] = __shfl(f1a, k+j);
#pragma unroll
      for (int j = 0; j < 8; ++j) a[j] = fmaf(av[j], wv[j], a[j]);
    }
    for (int k = 0; k < 64; k += 8) {
      float wv[8], av[8];
#pragma unroll
      for (int j = 0; j < 8; ++j) wv[j] = w[(64+k+j)*64];
#pragma unroll
      for (int j = 0; j < 8; ++j) av[j] = __shfl(f1b, k+j);
#pragma unroll
      for (int j = 0; j < 8; ++j) a[j] = fmaf(av[j], wv[j], a[j]);
    }
    f2 = ((a[0]+a[1])+(a[2]+a[3])) + ((a[4]+a[5])+(a[6]+a[7])) + fb2[p*64 + l];
  }
  // --- h1: K=64, 32 cols (lanes 0..31); dot hW2; reduce ---
  {
    float val = 0.f;
    float a[8] = {0.f,0.f,0.f,0.f,0.f,0.f,0.f,0.f};
    const float* w = hW1 + p*2048 + (l & 31);
    for (int k = 0; k < 64; k += 8) {
      float wv[8], av[8];
#pragma unroll
      for (int j = 0; j < 8; ++j) wv[j] = w[(k+j)*32];
#pragma unroll
      for (int j = 0; j < 8; ++j) av[j] = __shfl(f2, k+j);
#pragma unroll
      for (int j = 0; j < 8; ++j) a[j] = fmaf(av[j], wv[j], a[j]);
    }
    if (l < 32) {
      const float h1 = ((a[0]+a[1])+(a[2]+a[3])) + ((a[4]+a[5])+(a[6]+a[7])) + hb1[p*32 + l];
      val = fmaxf(h1, 0.f) * hW2[p*32 + l];
    }
#pragma unroll
    for (int o = 1; o < 32; o <<= 1) val += __shfl_xor(val, o);
    if (l == 0) out[p*1024 + b] = val + hb2[p];
  }
}

extern "C" void kernel_launch(void* const* d_in, const int* in_sizes, int n_in,
                              void* d_out, int out_size, void* d_ws, size_t ws_size,
                              hipStream_t stream) {
  const float* x_atoms    = (const float*)d_in[0];
  const float* pos        = (const float*)d_in[1];
  const float* molf       = (const float*)d_in[3];
  const float* emb_W      = (const float*)d_in[4];
  const float* emb_b      = (const float*)d_in[5];
  const float* mp_W1      = (const float*)d_in[6];
  const float* mp_b1      = (const float*)d_in[7];
  const float* mp_W2      = (const float*)d_in[8];
  const float* mp_b2      = (const float*)d_in[9];
  const float* ln_g       = (const float*)d_in[10];
  const float* ln_b       = (const float*)d_in[11];
  const float* attn_in_w  = (const float*)d_in[12];
  const float* attn_in_b  = (const float*)d_in[13];
  const float* attn_out_w = (const float*)d_in[14];
  const float* attn_out_b = (const float*)d_in[15];
  const float* pool_W     = (const float*)d_in[16];
  const float* pool_b     = (const float*)d_in[17];
  const float* mol_gate   = (const float*)d_in[18];
  const float* lrn_gate   = (const float*)d_in[19];
  const float* meW1       = (const float*)d_in[20];
  const float* meb1       = (const float*)d_in[21];
  const float* meW2       = (const float*)d_in[22];
  const float* meb2       = (const float*)d_in[23];
  const float* leW1       = (const float*)d_in[24];
  const float* leb1       = (const float*)d_in[25];
  const float* leW2       = (const float*)d_in[26];
  const float* leb2       = (const float*)d_in[27];
  const float* fW1        = (const float*)d_in[28];
  const float* fb1        = (const float*)d_in[29];
  const float* fW2        = (const float*)d_in[30];
  const float* fb2        = (const float*)d_in[31];
  const float* hW1        = (const float*)d_in[32];
  const float* hb1        = (const float*)d_in[33];
  const float* hW2        = (const float*)d_in[34];
  const float* hb2        = (const float*)d_in[35];
  const int*   ei         = (const int*)d_in[36];

  float* ws      = (float*)d_ws;
  float* x       = ws;                              // NN*128
  float* region  = x + (size_t)NN*128;              // NN*384 floats
  float* P       = region;                          // NN*128 fp32
  unsigned short* Qbf = (unsigned short*)(region + (size_t)NN*128); // NN*128 bf16
  float* dqkv    = region;                          // NN*384 (layer bufs dead)
  float* att     = region + (size_t)NN*384;         // NN*128
  float* csr_rf  = att + (size_t)NN*128;            // NE*4 floats (float4 records)
  float4* csr_rec = (float4*)csr_rf;
  int*   cnt_i   = (int*)(csr_rf + (size_t)NE*4);   // NN
  int*   csr_off = cnt_i + NN;                      // NN+64 (padded)
  int*   cur     = csr_off + NN + 64;               // NN
  float* pqbias  = (float*)(cur + NN);              // 768
  short* bh      = (short*)(pqbias + 768);          // PK_TOTAL shorts
  short* bl      = bh + PK_TOTAL;                   // PK_TOTAL shorts
  float* meW1g   = (float*)(bl + PK_TOTAL);         // 51200
  float* leW1g   = meW1g + 51200;                   // 16384

  hipMemsetAsync(cnt_i, 0, (size_t)NN*sizeof(int), stream);

  prep_kernel<<<(PK_TOTAL + 255)/256, 256, 0, stream>>>(
      mp_W1, mp_W2, attn_in_w, attn_out_w, emb_W, mp_b1, bh, bl, pqbias);
  gate_prep_kernel<<<(67584 + 255)/256, 256, 0, stream>>>(
      meW1, mol_gate, leW1, lrn_gate, meW1g, leW1g);
  hist_kernel<<<NE/256, 256, 0, stream>>>(ei, cnt_i);
  scan_kernel<<<1, 1024, 0, stream>>>(cnt_i, csr_off, cur);
  scatter_kernel<<<NE/256, 256, 0, stream>>>(pos, ei, cur, csr_rec);

  // embed via MFMA: x = x_atoms @ emb_W + emb_b
  mfma_gemm_kernel<<<dim3(NN/128, 2), 256, 0, stream>>>(
      x_atoms, 64, 64, bh + EMB_OFF, bl + EMB_OFF, emb_b, x, 128, 128, 0, nullptr);

  for (int l = 0; l < 3; ++l) {
    mfma_gemm_kernel<<<dim3(NN/128, 4), 256, 0, stream>>>(
        x, 128, 128, bh + W1AB_OFF + l*32768, bl + W1AB_OFF + l*32768,
        pqbias + l*256, P, 256, 128, 0, Qbf);
    agg_kernel<<<NN/4, 256, 0, stream>>>(P, Qbf, csr_off, csr_rec,
                                         mp_W1 + (size_t)l*259*128);
    mfma_gemm_ln_kernel<<<NN/64, 256, 0, stream>>>(
        P, 128, bh + W2_OFF + l*16384, bl + W2_OFF + l*16384,
        mp_b2 + l*128, csr_off, ln_g + l*128, ln_b + l*128, x);
  }

  // attention path
  mfma_gemm_kernel<<<dim3(NN/128, 6), 256, 0, stream>>>(
      x, 128, 128, bh + WIN_OFF, bl + WIN_OFF, attn_in_b, dqkv, 384, 384, 0, nullptr);
  attn_kernel<<<NB, 128, 0, stream>>>(dqkv);
  mfma_gemm_kernel<<<dim3(NN/128, 2), 256, 0, stream>>>(
      dqkv + 256, 384, 128, bh + WOUT_OFF, bl + WOUT_OFF, attn_out_b, att, 128, 128, 0, nullptr);

  // fused pooling + proj + wave-autonomous head
  pool_head_kernel<<<NB, 256, 0, stream>>>(
      att, x, pool_W, pool_b, molf,
      meW1g, meb1, meW2, meb2, leW1g, leb1, leW2, leb2,
      fW1, fb1, fW2, fb2, hW1, hb1, hW2, hb2, (float*)d_out);
}

// Round 14
// 383.885 us; speedup vs baseline: 1.0209x; 1.0209x over previous
//
#include <hip/hip_runtime.h>

#define NE 524288
#define NN 32768
#define NB 1024

#define F4(p) (*(const float4*)(p))

typedef __bf16 bf16x8 __attribute__((ext_vector_type(8)));
typedef float  f32x4  __attribute__((ext_vector_type(4)));

__device__ __forceinline__ float sigmoidf_(float v) { return 1.f / (1.f + expf(-v)); }

__device__ __forceinline__ void bf16split(float f, short &hi, short &lo) {
  unsigned u = __float_as_uint(f);
  unsigned rh = (u + 0x7FFFu + ((u >> 16) & 1u)) >> 16;
  float fh = __uint_as_float(rh << 16);
  float fl = f - fh;
  unsigned u2 = __float_as_uint(fl);
  unsigned rl = (u2 + 0x7FFFu + ((u2 >> 16) & 1u)) >> 16;
  hi = (short)rh; lo = (short)rl;
}

__device__ __forceinline__ unsigned short f2bf(float f) {
  unsigned u = __float_as_uint(f);
  return (unsigned short)((u + 0x7FFFu + ((u >> 16) & 1u)) >> 16);
}
__device__ __forceinline__ float bf2f(unsigned short h) {
  return __uint_as_float(((unsigned)h) << 16);
}

__device__ __forceinline__ void ld32(float* xr, const float* p) {
#pragma unroll
  for (int i = 0; i < 32; i += 4) {
    float4 v = F4(&p[i]);
    xr[i] = v.x; xr[i+1] = v.y; xr[i+2] = v.z; xr[i+3] = v.w;
  }
}

__device__ __forceinline__ float dot32r(const float* __restrict__ w, const float* xr) {
  float s = 0.f;
#pragma unroll
  for (int i = 0; i < 32; i += 4) {
    float4 ww = F4(&w[i]);
    s = fmaf(xr[i],   ww.x, s);
    s = fmaf(xr[i+1], ww.y, s);
    s = fmaf(xr[i+2], ww.z, s);
    s = fmaf(xr[i+3], ww.w, s);
  }
  return s;
}

// ---------------- CSR build ----------------
__global__ __launch_bounds__(256) void hist_kernel(const int* __restrict__ ei, int* __restrict__ cnt) {
  const int e = blockIdx.x*256 + threadIdx.x;
  atomicAdd(&cnt[ei[NE + e]], 1);
}

__global__ __launch_bounds__(1024) void scan_kernel(
    const int* __restrict__ cnt, int* __restrict__ off, int* __restrict__ cur)
{
  __shared__ int wsum[16];
  const int t = threadIdx.x;
  int local[32];
  const int base = t*32;
  int s = 0;
#pragma unroll
  for (int i = 0; i < 32; ++i) { local[i] = cnt[base+i]; s += local[i]; }
  int pre = s;
  const int lane = t & 63;
#pragma unroll
  for (int o = 1; o < 64; o <<= 1) { int v = __shfl_up(pre, o); if (lane >= o) pre += v; }
  if (lane == 63) wsum[t >> 6] = pre;
  __syncthreads();
  if (t == 0) { int a = 0; for (int w = 0; w < 16; ++w) { int v = wsum[w]; wsum[w] = a; a += v; } }
  __syncthreads();
  int excl = wsum[t >> 6] + pre - s;
#pragma unroll
  for (int i = 0; i < 32; ++i) { off[base+i] = excl; cur[base+i] = excl; excl += local[i]; }
  if (t == 1023) off[NN] = excl;
}

// edge record: {src_as_float, d, 1/(1+d), exp(-d)}
__global__ __launch_bounds__(256) void scatter_kernel(
    const float* __restrict__ pos, const int* __restrict__ ei,
    int* __restrict__ cur, float4* __restrict__ csr_rec)
{
  const int e = blockIdx.x*256 + threadIdx.x;
  const int s = ei[e];
  const int d = ei[NE + e];
  float dx = pos[d*3+0] - pos[s*3+0];
  float dy = pos[d*3+1] - pos[s*3+1];
  float dz = pos[d*3+2] - pos[s*3+2];
  float dist = sqrtf(dx*dx + dy*dy + dz*dz + 1e-12f);
  const int slot = atomicAdd(&cur[d], 1);
  csr_rec[slot] = make_float4(__int_as_float(s), dist, 1.f/(1.f + dist), expf(-dist));
}

// ---------------- weight prep: split-bf16, MFMA-frag-major ----------------
__device__ __forceinline__ void pack_decode(int r, int N, int &k, int &n) {
  const int j = r & 7, lane = (r >> 3) & 63, rest = r >> 9;
  const int NT = N >> 4;
  const int t = rest % NT, kc = rest / NT;
  k = kc*32 + (lane >> 4)*8 + j;
  n = t*16 + (lane & 15);
}

// segment offsets (elements)
#define W1AB_OFF 0        // l*32768, K=128 N=256
#define W2_OFF   98304    // l*16384, K=128 N=128
#define WIN_OFF  147456   // K=128 N=384
#define WOUT_OFF 196608   // K=128 N=128
#define EMB_OFF  212992   // K=64  N=128
#define PK_TOTAL 221184

__global__ __launch_bounds__(256) void prep_kernel(
    const float* __restrict__ mp_W1, const float* __restrict__ mp_W2,
    const float* __restrict__ win, const float* __restrict__ wout,
    const float* __restrict__ emb_W, const float* __restrict__ mp_b1,
    short* __restrict__ bh, short* __restrict__ bl, float* __restrict__ pqbias)
{
  const int i = blockIdx.x*256 + threadIdx.x;
  if (i < 768) { const int l = i >> 8, t = i & 255; pqbias[i] = t < 128 ? mp_b1[l*128 + t] : 0.f; }
  if (i >= PK_TOTAL) return;
  int k, n; float v;
  if (i < W2_OFF) {
    const int l = i / 32768, r = i % 32768;
    pack_decode(r, 256, k, n);
    const float* W = mp_W1 + (size_t)l*259*128;
    v = (n < 128) ? W[k*128 + n] : W[(128+k)*128 + (n-128)];
  } else if (i < WIN_OFF) {
    const int q = i - W2_OFF, l = q / 16384, r = q % 16384;
    pack_decode(r, 128, k, n);
    v = mp_W2[(size_t)l*16384 + k*128 + n];
  } else if (i < WOUT_OFF) {
    pack_decode(i - WIN_OFF, 384, k, n);
    v = win[n*128 + k];
  } else if (i < EMB_OFF) {
    pack_decode(i - WOUT_OFF, 128, k, n);
    v = wout[n*128 + k];
  } else {
    pack_decode(i - EMB_OFF, 128, k, n);   // K=64 segment: k < 64 by construction
    v = emb_W[k*128 + n];
  }
  short h_, lo; bf16split(v, h_, lo);
  bh[i] = h_; bl[i] = lo;
}

// ---------------- gate prep: fold input gates into head first-layer weights ----------------
__global__ __launch_bounds__(256) void gate_prep_kernel(
    const float* __restrict__ meW1, const float* __restrict__ mol_gate,
    const float* __restrict__ leW1, const float* __restrict__ lrn_gate,
    float* __restrict__ meW1g, float* __restrict__ leW1g)
{
  const int i = blockIdx.x*256 + threadIdx.x;
  if (i < 51200) {
    const int p = i / 12800, r = i % 12800, k = r >> 6;
    meW1g[i] = meW1[i] * sigmoidf_(mol_gate[p*200 + k]);
  } else if (i < 67584) {
    const int q = i - 51200;
    const int p = q / 4096, r = q % 4096, k = r >> 6;
    leW1g[q] = leW1[q] * sigmoidf_(lrn_gate[p*64 + k]);
  }
}

// ---------------- generic MFMA GEMM: C[M][·] = op(A[M][K] @ B + bias) ----------------
__global__ __launch_bounds__(256, 2) void mfma_gemm_kernel(
    const float* __restrict__ A, int lda, int K,
    const short* __restrict__ Bh, const short* __restrict__ Bl,
    const float* __restrict__ bias, float* __restrict__ C, int ncols, int ldc,
    int relu, unsigned short* __restrict__ qbf)
{
  const int lane = threadIdx.x & 63, wid = threadIdx.x >> 6;
  const int m0 = blockIdx.x * 128 + wid * 32;
  const int n0 = blockIdx.y * 64;
  const int NT = ncols >> 4;
  const int cl = lane & 15, kg = lane >> 4;
  const int KC = K >> 5;

  f32x4 acc[2][4];
#pragma unroll
  for (int s = 0; s < 2; ++s)
#pragma unroll
    for (int t = 0; t < 4; ++t) acc[s][t] = (f32x4){0.f,0.f,0.f,0.f};

  for (int kc = 0; kc < KC; ++kc) {
    bf16x8 Ah[2], Al[2];
#pragma unroll
    for (int s = 0; s < 2; ++s) {
      const float* ap = &A[(size_t)(m0 + s*16 + cl)*lda + kc*32 + kg*8];
      const float4 f0 = F4(ap), f1 = F4(ap + 4);
      const float fv[8] = {f0.x,f0.y,f0.z,f0.w,f1.x,f1.y,f1.z,f1.w};
      union { short s[8]; bf16x8 b; } uh, ul;
#pragma unroll
      for (int j = 0; j < 8; ++j) bf16split(fv[j], uh.s[j], ul.s[j]);
      Ah[s] = uh.b; Al[s] = ul.b;
    }
    bf16x8 Bfh[4], Bfl[4];
#pragma unroll
    for (int t = 0; t < 4; ++t) {
      const size_t off = (((size_t)(kc*NT + (n0 >> 4) + t))*64 + lane)*8;
      Bfh[t] = *(const bf16x8*)&Bh[off];
      Bfl[t] = *(const bf16x8*)&Bl[off];
    }
#pragma unroll
    for (int s = 0; s < 2; ++s)
#pragma unroll
      for (int t = 0; t < 4; ++t)
        acc[s][t] = __builtin_amdgcn_mfma_f32_16x16x32_bf16(Ah[s], Bfh[t], acc[s][t], 0, 0, 0);
#pragma unroll
    for (int s = 0; s < 2; ++s)
#pragma unroll
      for (int t = 0; t < 4; ++t)
        acc[s][t] = __builtin_amdgcn_mfma_f32_16x16x32_bf16(Ah[s], Bfl[t], acc[s][t], 0, 0, 0);
#pragma unroll
    for (int s = 0; s < 2; ++s)
#pragma unroll
      for (int t = 0; t < 4; ++t)
        acc[s][t] = __builtin_amdgcn_mfma_f32_16x16x32_bf16(Al[s], Bfh[t], acc[s][t], 0, 0, 0);
  }

#pragma unroll
  for (int t = 0; t < 4; ++t) {
    const int col = n0 + t*16 + cl;
    const float bv = bias[col];
#pragma unroll
    for (int s = 0; s < 2; ++s) {
      const int rbase = m0 + s*16 + kg*4;
#pragma unroll
      for (int r = 0; r < 4; ++r) {
        float v = acc[s][t][r] + bv;
        if (relu) v = fmaxf(v, 0.f);
        if (qbf && col >= 128)
          qbf[(size_t)(rbase + r)*128 + (col - 128)] = f2bf(v);
        else
          C[(size_t)(rbase + r)*ldc + col] = v;
      }
    }
  }
}

// ---------------- MFMA GEMM + residual + LN ----------------
__global__ __launch_bounds__(256, 2) void mfma_gemm_ln_kernel(
    const float* __restrict__ A, int lda,
    const short* __restrict__ Bh, const short* __restrict__ Bl,
    const float* __restrict__ b2, const int* __restrict__ csr_off,
    const float* __restrict__ g, const float* __restrict__ bb,
    float* __restrict__ x)
{
  const int lane = threadIdx.x & 63, wid = threadIdx.x >> 6;
  const int m0 = blockIdx.x * 64 + wid * 16;
  const int cl = lane & 15, kg = lane >> 4;

  bf16x8 Ah[4], Al[4];
#pragma unroll
  for (int kc = 0; kc < 4; ++kc) {
    const float* ap = &A[(size_t)(m0 + cl)*lda + kc*32 + kg*8];
    const float4 f0 = F4(ap), f1 = F4(ap + 4);
    const float fv[8] = {f0.x,f0.y,f0.z,f0.w,f1.x,f1.y,f1.z,f1.w};
    union { short s[8]; bf16x8 b; } uh, ul;
#pragma unroll
    for (int j = 0; j < 8; ++j) bf16split(fv[j], uh.s[j], ul.s[j]);
    Ah[kc] = uh.b; Al[kc] = ul.b;
  }

  f32x4 acc[8];
#pragma unroll
  for (int t = 0; t < 8; ++t) acc[t] = (f32x4){0.f,0.f,0.f,0.f};

#pragma unroll
  for (int kc = 0; kc < 4; ++kc) {
    bf16x8 Bfh[8], Bfl[8];
#pragma unroll
    for (int t = 0; t < 8; ++t) {
      const size_t off = (((size_t)(kc*8 + t))*64 + lane)*8;
      Bfh[t] = *(const bf16x8*)&Bh[off];
      Bfl[t] = *(const bf16x8*)&Bl[off];
    }
#pragma unroll
    for (int t = 0; t < 8; ++t)
      acc[t] = __builtin_amdgcn_mfma_f32_16x16x32_bf16(Ah[kc], Bfh[t], acc[t], 0, 0, 0);
#pragma unroll
    for (int t = 0; t < 8; ++t)
      acc[t] = __builtin_amdgcn_mfma_f32_16x16x32_bf16(Ah[kc], Bfl[t], acc[t], 0, 0, 0);
#pragma unroll
    for (int t = 0; t < 8; ++t)
      acc[t] = __builtin_amdgcn_mfma_f32_16x16x32_bf16(Al[kc], Bfh[t], acc[t], 0, 0, 0);
  }

  const int r0 = m0 + kg*4;
  float sflag[4];
#pragma unroll
  for (int r = 0; r < 4; ++r)
    sflag[r] = (csr_off[r0 + r + 1] > csr_off[r0 + r]) ? 1.f : 0.f;

  float ps[4] = {0.f,0.f,0.f,0.f}, pq[4] = {0.f,0.f,0.f,0.f};
  float yv[8][4];
#pragma unroll
  for (int t = 0; t < 8; ++t) {
    const int col = t*16 + cl;
    const float b2v = b2[col];
#pragma unroll
    for (int r = 0; r < 4; ++r) {
      const float y = acc[t][r] + sflag[r]*b2v + x[(size_t)(r0 + r)*128 + col];
      yv[t][r] = y;
      ps[r] += y;
      pq[r] = fmaf(y, y, pq[r]);
    }
  }
#pragma unroll
  for (int o = 1; o < 16; o <<= 1) {
#pragma unroll
    for (int r = 0; r < 4; ++r) { ps[r] += __shfl_xor(ps[r], o); pq[r] += __shfl_xor(pq[r], o); }
  }
#pragma unroll
  for (int r = 0; r < 4; ++r) {
    const float mu = ps[r] * (1.f/128.f);
    const float var = pq[r]*(1.f/128.f) - mu*mu;
    const float rstd = rsqrtf(var + 1e-5f);
#pragma unroll
    for (int t = 0; t < 8; ++t) {
      const int col = t*16 + cl;
      x[(size_t)(r0 + r)*128 + col] = (yv[t][r] - mu)*rstd*g[col] + bb[col];
    }
  }
}

// ---------------- aggregation: P[n] <- mean_e relu(P[n]+Qbf[src]+df@W1c) ----------------
__global__ __launch_bounds__(256, 6) void agg_kernel(
    float* __restrict__ P, const unsigned short* __restrict__ Qbf,
    const int* __restrict__ csr_off, const float4* __restrict__ csr_rec,
    const float* __restrict__ W1)
{
  const int tid = threadIdx.x;
  const int node = blockIdx.x*4 + (tid >> 6);
  const int lane = tid & 63;
  const int c0 = lane*2;
  const int off0 = csr_off[node], off1 = csr_off[node+1];

  const float* __restrict__ w1c = W1 + 256*128;
  const float w00 = w1c[c0],       w01 = w1c[c0+1];
  const float w10 = w1c[128+c0],   w11 = w1c[128+c0+1];
  const float w20 = w1c[256+c0],   w21 = w1c[256+c0+1];
  const float2 p = *(const float2*)&P[(size_t)node*128 + c0];

  float a0 = 0.f, a1 = 0.f;
  int e = off0;
  for (; e + 8 <= off1; e += 8) {
    float4 rc[8];
#pragma unroll
    for (int j = 0; j < 8; ++j) rc[j] = csr_rec[e+j];
    ushort2 qv[8];
#pragma unroll
    for (int j = 0; j < 8; ++j)
      qv[j] = *(const ushort2*)&Qbf[(size_t)__float_as_int(rc[j].x)*128 + c0];
#pragma unroll
    for (int j = 0; j < 8; ++j) {
      float h0 = p.x + bf2f(qv[j].x);
      h0 = fmaf(rc[j].y, w00, h0); h0 = fmaf(rc[j].z, w10, h0); h0 = fmaf(rc[j].w, w20, h0);
      float h1 = p.y + bf2f(qv[j].y);
      h1 = fmaf(rc[j].y, w01, h1); h1 = fmaf(rc[j].z, w11, h1); h1 = fmaf(rc[j].w, w21, h1);
      a0 += fmaxf(h0, 0.f);
      a1 += fmaxf(h1, 0.f);
    }
  }
  for (; e < off1; ++e) {
    const float4 rc = csr_rec[e];
    const ushort2 qv = *(const ushort2*)&Qbf[(size_t)__float_as_int(rc.x)*128 + c0];
    float h0 = p.x + bf2f(qv.x);
    h0 = fmaf(rc.y, w00, h0); h0 = fmaf(rc.z, w10, h0); h0 = fmaf(rc.w, w20, h0);
    float h1 = p.y + bf2f(qv.y);
    h1 = fmaf(rc.y, w01, h1); h1 = fmaf(rc.z, w11, h1); h1 = fmaf(rc.w, w21, h1);
    a0 += fmaxf(h0, 0.f);
    a1 += fmaxf(h1, 0.f);
  }
  const int deg = off1 - off0;
  const float rc_ = deg > 0 ? 1.f/(float)deg : 1.f;
  *(float2*)&P[(size_t)node*128 + c0] = make_float2(a0*rc_, a1*rc_);
}

// ---------------- per-molecule attention on dqkv[n][384]; O -> dv slot ----------------
__global__ __launch_bounds__(128) void attn_kernel(float* __restrict__ dqkv)
{
  __shared__ float sk[32*132];
  __shared__ float sv[32*132];
  const int tid = threadIdx.x;
  const int b = blockIdx.x;

  for (int idx = tid; idx < 1024; idx += 128) {
    const int a = idx >> 5, c4 = idx & 31;
    *(float4*)&sk[a*132 + c4*4] = F4(&dqkv[(size_t)(b*32+a)*384 + 128 + c4*4]);
    *(float4*)&sv[a*132 + c4*4] = F4(&dqkv[(size_t)(b*32+a)*384 + 256 + c4*4]);
  }
  __syncthreads();

  const int h = tid >> 5, qr = tid & 31;
  float qreg[32];
  ld32(qreg, &dqkv[(size_t)(b*32+qr)*384 + h*32]);

  float sc[32];
#pragma unroll
  for (int k = 0; k < 32; ++k)
    sc[k] = dot32r(&sk[k*132 + h*32], qreg) * 0.17677669529663687f;
  float mx = sc[0];
#pragma unroll
  for (int k = 1; k < 32; ++k) mx = fmaxf(mx, sc[k]);
  float se = 0.f;
#pragma unroll
  for (int k = 0; k < 32; ++k) { sc[k] = expf(sc[k] - mx); se += sc[k]; }
  const float inv = 1.f / se;

  __syncthreads();

  float od[32];
#pragma unroll
  for (int i = 0; i < 32; ++i) od[i] = 0.f;
#pragma unroll 4
  for (int k = 0; k < 32; ++k) {
    const float w = sc[k] * inv;
    const float* vr = &sv[k*132 + h*32];
#pragma unroll
    for (int i = 0; i < 32; i += 4) {
      float4 v = F4(&vr[i]);
      od[i]   = fmaf(w, v.x, od[i]);
      od[i+1] = fmaf(w, v.y, od[i+1]);
      od[i+2] = fmaf(w, v.z, od[i+2]);
      od[i+3] = fmaf(w, v.w, od[i+3]);
    }
  }
#pragma unroll
  for (int i = 0; i < 32; i += 4)
    *(float4*)&sk[qr*132 + h*32 + i] = make_float4(od[i], od[i+1], od[i+2], od[i+3]);
  __syncthreads();

  for (int idx = tid; idx < 1024; idx += 128) {
    const int a = idx >> 5, c4 = idx & 31;
    *(float4*)&dqkv[(size_t)(b*32+a)*384 + 256 + c4*4] = F4(&sk[a*132 + c4*4]);
  }
}

// ---------------- fused pooling + proj + head: 2 molecules/block, shared weight streams ----
// block = 256 threads = 2 molecules. Pool: 128 threads per molecule. Head: wave = property,
// each wave computes BOTH molecules' chains from one weight stream (L2 traffic halved).
__global__ __launch_bounds__(256) void pool_head2_kernel(
    const float* __restrict__ att, const float* __restrict__ x,
    const float* __restrict__ pW, const float* __restrict__ pb,
    const float* __restrict__ molf,
    const float* __restrict__ meW1g, const float* __restrict__ meb1,
    const float* __restrict__ meW2, const float* __restrict__ meb2,
    const float* __restrict__ leW1g, const float* __restrict__ leb1,
    const float* __restrict__ leW2, const float* __restrict__ leb2,
    const float* __restrict__ fW1, const float* __restrict__ fb1,
    const float* __restrict__ fW2, const float* __restrict__ fb2,
    const float* __restrict__ hW1, const float* __restrict__ hb1,
    const float* __restrict__ hW2, const float* __restrict__ hb2,
    float* __restrict__ out)
{
  const int b2 = blockIdx.x * 2, tid = threadIdx.x;
  __shared__ float satt[8448];   // [2][32][132]
  __shared__ float sx[8448];     // [2][32][132]
  __shared__ float aw_l[64];     // [2][32]
  __shared__ float spool[1024];  // [2][4][128]
  __shared__ float slrn[128];    // [2][64]
  __shared__ float sexpl[256];   // [2][128]
  __shared__ float smolf[400];   // [2][200]

  for (int idx = tid; idx < 2048; idx += 256) {
    const int m = idx >> 10, r = idx & 1023;
    const int a = r >> 5, c4 = r & 31;
    *(float4*)&satt[m*4224 + a*132 + c4*4] = F4(&att[(size_t)((b2+m)*32+a)*128 + c4*4]);
    *(float4*)&sx[m*4224 + a*132 + c4*4]   = F4(&x[(size_t)((b2+m)*32+a)*128 + c4*4]);
  }
  for (int i = tid; i < 400; i += 256) {
    const int m = i / 200, k = i - m*200;
    smolf[i] = molf[(size_t)(b2+m)*200 + k];
  }
  __syncthreads();

  const int hh = tid >> 7, t2 = tid & 127;

  { // aw logits: 4 threads/row, 32 rows per molecule half
    const int a = t2 >> 2, q4 = t2 & 3;
    const float* sa = &satt[hh*4224 + a*132 + q4*32];
    const float* sb = &sx[hh*4224 + a*132 + q4*32];
    float sp = 0.f;
#pragma unroll
    for (int i = 0; i < 32; ++i) sp = fmaf(sa[i], sb[i], sp);
    sp += __shfl_xor(sp, 1);
    sp += __shfl_xor(sp, 2);
    if (q4 == 0) aw_l[hh*32 + a] = sp;
  }
  __syncthreads();

  { // pooling: 1 column/thread, both molecules in parallel
    float awr[32];
    float mxl = aw_l[hh*32];
#pragma unroll
    for (int a = 1; a < 32; ++a) mxl = fmaxf(mxl, aw_l[hh*32 + a]);
    float se = 0.f;
#pragma unroll
    for (int a = 0; a < 32; ++a) { awr[a] = expf(aw_l[hh*32 + a] - mxl); se += awr[a]; }
    const float inv = 1.f / se;
    const int c = t2;
    float mx = -3.4e38f, sm = 0.f, wm = 0.f, ex = 0.f;
#pragma unroll
    for (int a = 0; a < 32; ++a) {
      const float v = satt[hh*4224 + a*132 + c];
      mx = fmaxf(mx, v);
      sm += v;
      wm = fmaf(v, awr[a], wm);
      ex += sx[hh*4224 + a*132 + c];
    }
    wm *= inv;
    const float mean = sm * 0.03125f;
    float s2 = 0.f;
#pragma unroll
    for (int a = 0; a < 32; ++a) {
      const float d = satt[hh*4224 + a*132 + c] - mean;
      s2 = fmaf(d, d, s2);
    }
    const float stdp = sqrtf(s2 * (1.f/31.f));  // ddof=1
    sexpl[hh*128 + c]       = ex * 0.03125f;
    spool[hh*512 + c]       = wm;
    spool[hh*512 + 128 + c] = mx;
    spool[hh*512 + 256 + c] = mean;
    spool[hh*512 + 384 + c] = stdp;
  }
  __syncthreads();

  if (t2 < 64) { // proj -> slrn (both molecules)
    const int k = t2 >> 4, qq = t2 & 15;
    const float* pk = pW + k*2048;
    const float* sp_ = &spool[hh*512 + k*128];
    float s0 = 0.f, s1 = 0.f, s2 = 0.f, s3 = 0.f;
    for (int h2 = 0; h2 < 128; h2 += 4) {
      s0 = fmaf(sp_[h2],   pk[h2*16 + qq],     s0);
      s1 = fmaf(sp_[h2+1], pk[(h2+1)*16 + qq], s1);
      s2 = fmaf(sp_[h2+2], pk[(h2+2)*16 + qq], s2);
      s3 = fmaf(sp_[h2+3], pk[(h2+3)*16 + qq], s3);
    }
    slrn[hh*64 + t2] = pb[k*16 + qq] + (s0+s1) + (s2+s3);
  }
  __syncthreads();  // head inputs published; head phase barrier-free below

  const int p = tid >> 6, l = tid & 63;

  // --- me1 (K=200): both molecules off one weight stream ---
  float m1_0, m1_1;
  {
    const float* w = meW1g + p*12800 + l;
    float a0[8] = {0,0,0,0,0,0,0,0}, a1[8] = {0,0,0,0,0,0,0,0};
    for (int k = 0; k < 200; k += 8) {
      float wv[8], u0[8], u1[8];
#pragma unroll
      for (int j = 0; j < 8; ++j) wv[j] = w[(k+j)*64];
#pragma unroll
      for (int j = 0; j < 8; ++j) { u0[j] = smolf[k+j]; u1[j] = smolf[200+k+j]; }
#pragma unroll
      for (int j = 0; j < 8; ++j) {
        a0[j] = fmaf(u0[j], wv[j], a0[j]);
        a1[j] = fmaf(u1[j], wv[j], a1[j]);
      }
    }
    const float bv = meb1[p*64 + l];
    m1_0 = fmaxf(((a0[0]+a0[1])+(a0[2]+a0[3])) + ((a0[4]+a0[5])+(a0[6]+a0[7])) + bv, 0.f);
    m1_1 = fmaxf(((a1[0]+a1[1])+(a1[2]+a1[3])) + ((a1[4]+a1[5])+(a1[6]+a1[7])) + bv, 0.f);
  }
  // --- le1 (K=64) ---
  float l1_0, l1_1;
  {
    const float* w = leW1g + p*4096 + l;
    float a0[8] = {0,0,0,0,0,0,0,0}, a1[8] = {0,0,0,0,0,0,0,0};
    for (int k = 0; k < 64; k += 8) {
      float wv[8], u0[8], u1[8];
#pragma unroll
      for (int j = 0; j < 8; ++j) wv[j] = w[(k+j)*64];
#pragma unroll
      for (int j = 0; j < 8; ++j) { u0[j] = slrn[k+j]; u1[j] = slrn[64+k+j]; }
#pragma unroll
      for (int j = 0; j < 8; ++j) {
        a0[j] = fmaf(u0[j], wv[j], a0[j]);
        a1[j] = fmaf(u1[j], wv[j], a1[j]);
      }
    }
    const float bv = leb1[p*64 + l];
    l1_0 = fmaxf(((a0[0]+a0[1])+(a0[2]+a0[3])) + ((a0[4]+a0[5])+(a0[6]+a0[7])) + bv, 0.f);
    l1_1 = fmaxf(((a1[0]+a1[1])+(a1[2]+a1[3])) + ((a1[4]+a1[5])+(a1[6]+a1[7])) + bv, 0.f);
  }
  // --- me2 (K=64), both molecules ---
  float m2_0, m2_1;
  {
    const float* w = meW2 + p*4096 + l;
    float a0[8] = {0,0,0,0,0,0,0,0}, a1[8] = {0,0,0,0,0,0,0,0};
    for (int k = 0; k < 64; k += 8) {
      float wv[8], u0[8], u1[8];
#pragma unroll
      for (int j = 0; j < 8; ++j) wv[j] = w[(k+j)*64];
#pragma unroll
      for (int j = 0; j < 8; ++j) { u0[j] = __shfl(m1_0, k+j); u1[j] = __shfl(m1_1, k+j); }
#pragma unroll
      for (int j = 0; j < 8; ++j) {
        a0[j] = fmaf(u0[j], wv[j], a0[j]);
        a1[j] = fmaf(u1[j], wv[j], a1[j]);
      }
    }
    const float bv = meb2[p*64 + l];
    m2_0 = ((a0[0]+a0[1])+(a0[2]+a0[3])) + ((a0[4]+a0[5])+(a0[6]+a0[7])) + bv;
    m2_1 = ((a1[0]+a1[1])+(a1[2]+a1[3])) + ((a1[4]+a1[5])+(a1[6]+a1[7])) + bv;
  }
  // --- le2 (K=64), both molecules ---
  float l2_0, l2_1;
  {
    const float* w = leW2 + p*4096 + l;
    float a0[8] = {0,0,0,0,0,0,0,0}, a1[8] = {0,0,0,0,0,0,0,0};
    for (int k = 0; k < 64; k += 8) {
      float wv[8], u0[8], u1[8];
#pragma unroll
      for (int j = 0; j < 8; ++j) wv[j] = w[(k+j)*64];
#pragma unroll
      for (int j = 0; j < 8; ++j) { u0[j] = __shfl(l1_0, k+j); u1[j] = __shfl(l1_1, k+j); }
#pragma unroll
      for (int j = 0; j < 8; ++j) {
        a0[j] = fmaf(u0[j], wv[j], a0[j]);
        a1[j] = fmaf(u1[j], wv[j], a1[j]);
      }
    }
    const float bv = leb2[p*64 + l];
    l2_0 = ((a0[0]+a0[1])+(a0[2]+a0[3])) + ((a0[4]+a0[5])+(a0[6]+a0[7])) + bv;
    l2_1 = ((a1[0]+a1[1])+(a1[2]+a1[3])) + ((a1[4]+a1[5])+(a1[6]+a1[7])) + bv;
  }
  // --- fus1 (K=256: expl LDS | m2 shfl | l2 shfl), cols l and l+64, both mols ---
  float f1a_0, f1a_1, f1b_0, f1b_1;
  {
    const float* w = fW1 + p*32768;
    float a0[8]={0,0,0,0,0,0,0,0}, a1[8]={0,0,0,0,0,0,0,0};
    float c0[8]={0,0,0,0,0,0,0,0}, c1[8]={0,0,0,0,0,0,0,0};
    for (int k = 0; k < 128; k += 8) {
      float w0[8], w1[8], u0[8], u1[8];
#pragma unroll
      for (int j = 0; j < 8; ++j) w0[j] = w[(k+j)*128 + l];
#pragma unroll
      for (int j = 0; j < 8; ++j) w1[j] = w[(k+j)*128 + 64 + l];
#pragma unroll
      for (int j = 0; j < 8; ++j) { u0[j] = sexpl[k+j]; u1[j] = sexpl[128+k+j]; }
#pragma unroll
      for (int j = 0; j < 8; ++j) {
        a0[j] = fmaf(u0[j], w0[j], a0[j]);  a1[j] = fmaf(u1[j], w0[j], a1[j]);
        c0[j] = fmaf(u0[j], w1[j], c0[j]);  c1[j] = fmaf(u1[j], w1[j], c1[j]);
      }
    }
    for (int k = 0; k < 64; k += 8) {
      float w0[8], w1[8], u0[8], u1[8];
#pragma unroll
      for (int j = 0; j < 8; ++j) w0[j] = w[(128+k+j)*128 + l];
#pragma unroll
      for (int j = 0; j < 8; ++j) w1[j] = w[(128+k+j)*128 + 64 + l];
#pragma unroll
      for (int j = 0; j < 8; ++j) { u0[j] = __shfl(m2_0, k+j); u1[j] = __shfl(m2_1, k+j); }
#pragma unroll
      for (int j = 0; j < 8; ++j) {
        a0[j] = fmaf(u0[j], w0[j], a0[j]);  a1[j] = fmaf(u1[j], w0[j], a1[j]);
        c0[j] = fmaf(u0[j], w1[j], c0[j]);  c1[j] = fmaf(u1[j], w1[j], c1[j]);
      }
    }
    for (int k = 0; k < 64; k += 8) {
      float w0[8], w1[8], u0[8], u1[8];
#pragma unroll
      for (int j = 0; j < 8; ++j) w0[j] = w[(192+k+j)*128 + l];
#pragma unroll
      for (int j = 0; j < 8; ++j) w1[j] = w[(192+k+j)*128 + 64 + l];
#pragma unroll
      for (int j = 0; j < 8; ++j) { u0[j] = __shfl(l2_0, k+j); u1[j] = __shfl(l2_1, k+j); }
#pragma unroll
      for (int j = 0; j < 8; ++j) {
        a0[j] = fmaf(u0[j], w0[j], a0[j]);  a1[j] = fmaf(u1[j], w0[j], a1[j]);
        c0[j] = fmaf(u0[j], w1[j], c0[j]);  c1[j] = fmaf(u1[j], w1[j], c1[j]);
      }
    }
    const float ba = fb1[p*128 + l], bc = fb1[p*128 + 64 + l];
    f1a_0 = fmaxf(((a0[0]+a0[1])+(a0[2]+a0[3])) + ((a0[4]+a0[5])+(a0[6]+a0[7])) + ba, 0.f);
    f1a_1 = fmaxf(((a1[0]+a1[1])+(a1[2]+a1[3])) + ((a1[4]+a1[5])+(a1[6]+a1[7])) + ba, 0.f);
    f1b_0 = fmaxf(((c0[0]+c0[1])+(c0[2]+c0[3])) + ((c0[4]+c0[5])+(c0[6]+c0[7])) + bc, 0.f);
    f1b_1 = fmaxf(((c1[0]+c1[1])+(c1[2]+c1[3])) + ((c1[4]+c1[5])+(c1[6]+c1[7])) + bc, 0.f);
  }
  // --- fus2 (K=128) ---
  float f2_0, f2_1;
  {
    const float* w = fW2 + p*8192 + l;
    float a0[8]={0,0,0,0,0,0,0,0}, a1[8]={0,0,0,0,0,0,0,0};
    for (int k = 0; k < 64; k += 8) {
      float wv[8], u0[8], u1[8];
#pragma unroll
      for (int j = 0; j < 8; ++j) wv[j] = w[(k+j)*64];
#pragma unroll
      for (int j = 0; j < 8; ++j) { u0[j] = __shfl(f1a_0, k+j); u1[j] = __shfl(f1a_1, k+j); }
#pragma unroll
      for (int j = 0; j < 8; ++j) {
        a0[j] = fmaf(u0[j], wv[j], a0[j]);
        a1[j] = fmaf(u1[j], wv[j], a1[j]);
      }
    }
    for (int k = 0; k < 64; k += 8) {
      float wv[8], u0[8], u1[8];
#pragma unroll
      for (int j = 0; j < 8; ++j) wv[j] = w[(64+k+j)*64];
#pragma unroll
      for (int j = 0; j < 8; ++j) { u0[j] = __shfl(f1b_0, k+j); u1[j] = __shfl(f1b_1, k+j); }
#pragma unroll
      for (int j = 0; j < 8; ++j) {
        a0[j] = fmaf(u0[j], wv[j], a0[j]);
        a1[j] = fmaf(u1[j], wv[j], a1[j]);
      }
    }
    const float bv = fb2[p*64 + l];
    f2_0 = ((a0[0]+a0[1])+(a0[2]+a0[3])) + ((a0[4]+a0[5])+(a0[6]+a0[7])) + bv;
    f2_1 = ((a1[0]+a1[1])+(a1[2]+a1[3])) + ((a1[4]+a1[5])+(a1[6]+a1[7])) + bv;
  }
  // --- h1 (K=64) + dot hW2 + reduce, both molecules ---
  {
    const float* w = hW1 + p*2048 + (l & 31);
    float a0[8]={0,0,0,0,0,0,0,0}, a1[8]={0,0,0,0,0,0,0,0};
    for (int k = 0; k < 64; k += 8) {
      float wv[8], u0[8], u1[8];
#pragma unroll
      for (int j = 0; j < 8; ++j) wv[j] = w[(k+j)*32];
#pragma unroll
      for (int j = 0; j < 8; ++j) { u0[j] = __shfl(f2_0, k+j); u1[j] = __shfl(f2_1, k+j); }
#pragma unroll
      for (int j = 0; j < 8; ++j) {
        a0[j] = fmaf(u0[j], wv[j], a0[j]);
        a1[j] = fmaf(u1[j], wv[j], a1[j]);
      }
    }
    float v0 = 0.f, v1 = 0.f;
    if (l < 32) {
      const float hb = hb1[p*32 + l], w2v = hW2[p*32 + l];
      v0 = fmaxf(((a0[0]+a0[1])+(a0[2]+a0[3])) + ((a0[4]+a0[5])+(a0[6]+a0[7])) + hb, 0.f) * w2v;
      v1 = fmaxf(((a1[0]+a1[1])+(a1[2]+a1[3])) + ((a1[4]+a1[5])+(a1[6]+a1[7])) + hb, 0.f) * w2v;
    }
#pragma unroll
    for (int o = 1; o < 32; o <<= 1) { v0 += __shfl_xor(v0, o); v1 += __shfl_xor(v1, o); }
    if (l == 0) {
      const float hb2v = hb2[p];
      out[p*1024 + b2 + 0] = v0 + hb2v;
      out[p*1024 + b2 + 1] = v1 + hb2v;
    }
  }
}

extern "C" void kernel_launch(void* const* d_in, const int* in_sizes, int n_in,
                              void* d_out, int out_size, void* d_ws, size_t ws_size,
                              hipStream_t stream) {
  const float* x_atoms    = (const float*)d_in[0];
  const float* pos        = (const float*)d_in[1];
  const float* molf       = (const float*)d_in[3];
  const float* emb_W      = (const float*)d_in[4];
  const float* emb_b      = (const float*)d_in[5];
  const float* mp_W1      = (const float*)d_in[6];
  const float* mp_b1      = (const float*)d_in[7];
  const float* mp_W2      = (const float*)d_in[8];
  const float* mp_b2      = (const float*)d_in[9];
  const float* ln_g       = (const float*)d_in[10];
  const float* ln_b       = (const float*)d_in[11];
  const float* attn_in_w  = (const float*)d_in[12];
  const float* attn_in_b  = (const float*)d_in[13];
  const float* attn_out_w = (const float*)d_in[14];
  const float* attn_out_b = (const float*)d_in[15];
  const float* pool_W     = (const float*)d_in[16];
  const float* pool_b     = (const float*)d_in[17];
  const float* mol_gate   = (const float*)d_in[18];
  const float* lrn_gate   = (const float*)d_in[19];
  const float* meW1       = (const float*)d_in[20];
  const float* meb1       = (const float*)d_in[21];
  const float* meW2       = (const float*)d_in[22];
  const float* meb2       = (const float*)d_in[23];
  const float* leW1       = (const float*)d_in[24];
  const float* leb1       = (const float*)d_in[25];
  const float* leW2       = (const float*)d_in[26];
  const float* leb2       = (const float*)d_in[27];
  const float* fW1        = (const float*)d_in[28];
  const float* fb1        = (const float*)d_in[29];
  const float* fW2        = (const float*)d_in[30];
  const float* fb2        = (const float*)d_in[31];
  const float* hW1        = (const float*)d_in[32];
  const float* hb1        = (const float*)d_in[33];
  const float* hW2        = (const float*)d_in[34];
  const float* hb2        = (const float*)d_in[35];
  const int*   ei         = (const int*)d_in[36];

  float* ws      = (float*)d_ws;
  float* x       = ws;                              // NN*128
  float* region  = x + (size_t)NN*128;              // NN*384 floats
  float* P       = region;                          // NN*128 fp32
  unsigned short* Qbf = (unsigned short*)(region + (size_t)NN*128); // NN*128 bf16
  float* dqkv    = region;                          // NN*384 (layer bufs dead)
  float* att     = region + (size_t)NN*384;         // NN*128
  float* csr_rf  = att + (size_t)NN*128;            // NE*4 floats (float4 records)
  float4* csr_rec = (float4*)csr_rf;
  int*   cnt_i   = (int*)(csr_rf + (size_t)NE*4);   // NN
  int*   csr_off = cnt_i + NN;                      // NN+64 (padded)
  int*   cur     = csr_off + NN + 64;               // NN
  float* pqbias  = (float*)(cur + NN);              // 768
  short* bh      = (short*)(pqbias + 768);          // PK_TOTAL shorts
  short* bl      = bh + PK_TOTAL;                   // PK_TOTAL shorts
  float* meW1g   = (float*)(bl + PK_TOTAL);         // 51200
  float* leW1g   = meW1g + 51200;                   // 16384

  hipMemsetAsync(cnt_i, 0, (size_t)NN*sizeof(int), stream);

  prep_kernel<<<(PK_TOTAL + 255)/256, 256, 0, stream>>>(
      mp_W1, mp_W2, attn_in_w, attn_out_w, emb_W, mp_b1, bh, bl, pqbias);
  gate_prep_kernel<<<(67584 + 255)/256, 256, 0, stream>>>(
      meW1, mol_gate, leW1, lrn_gate, meW1g, leW1g);
  hist_kernel<<<NE/256, 256, 0, stream>>>(ei, cnt_i);
  scan_kernel<<<1, 1024, 0, stream>>>(cnt_i, csr_off, cur);
  scatter_kernel<<<NE/256, 256, 0, stream>>>(pos, ei, cur, csr_rec);

  // embed via MFMA: x = x_atoms @ emb_W + emb_b
  mfma_gemm_kernel<<<dim3(NN/128, 2), 256, 0, stream>>>(
      x_atoms, 64, 64, bh + EMB_OFF, bl + EMB_OFF, emb_b, x, 128, 128, 0, nullptr);

  for (int l = 0; l < 3; ++l) {
    mfma_gemm_kernel<<<dim3(NN/128, 4), 256, 0, stream>>>(
        x, 128, 128, bh + W1AB_OFF + l*32768, bl + W1AB_OFF + l*32768,
        pqbias + l*256, P, 256, 128, 0, Qbf);
    agg_kernel<<<NN/4, 256, 0, stream>>>(P, Qbf, csr_off, csr_rec,
                                         mp_W1 + (size_t)l*259*128);
    mfma_gemm_ln_kernel<<<NN/64, 256, 0, stream>>>(
        P, 128, bh + W2_OFF + l*16384, bl + W2_OFF + l*16384,
        mp_b2 + l*128, csr_off, ln_g + l*128, ln_b + l*128, x);
  }

  // attention path
  mfma_gemm_kernel<<<dim3(NN/128, 6), 256, 0, stream>>>(
      x, 128, 128, bh + WIN_OFF, bl + WIN_OFF, attn_in_b, dqkv, 384, 384, 0, nullptr);
  attn_kernel<<<NB, 128, 0, stream>>>(dqkv);
  mfma_gemm_kernel<<<dim3(NN/128, 2), 256, 0, stream>>>(
      dqkv + 256, 384, 128, bh + WOUT_OFF, bl + WOUT_OFF, attn_out_b, att, 128, 128, 0, nullptr);

  // fused pooling + proj + head: 2 molecules/block, shared weight streams
  pool_head2_kernel<<<NB/2, 256, 0, stream>>>(
      att, x, pool_W, pool_b, molf,
      meW1g, meb1, meW2, meb2, leW1g, leb1, leW2, leb2,
      fW1, fb1, fW2, fb2, hW1, hb1, hW2, hb2, (float*)d_out);
}